// Round 8
// baseline (29885.928 us; speedup 1.0000x reference)
//
#include <hip/hip_runtime.h>

typedef short  short8 __attribute__((ext_vector_type(8)));
typedef float  f32x4  __attribute__((ext_vector_type(4)));
typedef float  f32x2  __attribute__((ext_vector_type(2)));
typedef _Float16 half8_t __attribute__((ext_vector_type(8)));
typedef unsigned int u32x2 __attribute__((ext_vector_type(2)));

#define T_STEPS 2048
#define I_DIM   2048
#define H_DIM   4096
#define G_DIM   16384   // 4*H
#define W_SCALE     256.0f
#define W_INV_SCALE (1.0f / 256.0f)
#define FLAG_STRIDE 32  // u32 stride between flags (128B -> one L3 line each)

__device__ __forceinline__ unsigned short f2bf(float x) {
    union { float f; unsigned int u; } v; v.f = x;
    unsigned int u = v.u;
    return (unsigned short)((u + 0x7FFFu + ((u >> 16) & 1u)) >> 16);
}
__device__ __forceinline__ float sigmoidf_(float x) {
    return 1.0f / (1.0f + __expf(-x));
}

// ---- OCP e4m3 decode (hot path uses HW cvt; word-select must be a
// compile-time literal -> template parameter, r7 compile-fix) ----
__device__ __forceinline__ float dec1_e4m3(unsigned b) {
    int e = (b >> 3) & 15, m = b & 7;
    float v = (e == 0) ? ldexpf((float)m, -9) : ldexpf((float)(8 + m), e - 10);
    return (b & 0x80) ? -v : v;
}
template <bool HI>
__device__ __forceinline__ f32x2 fp8pair_f32(unsigned w) {
#if __has_builtin(__builtin_amdgcn_cvt_pk_f32_fp8)
    return __builtin_amdgcn_cvt_pk_f32_fp8((int)w, HI);
#else
    unsigned sh = HI ? 16u : 0u;
    f32x2 r;
    r[0] = dec1_e4m3((w >> sh) & 0xFF);
    r[1] = dec1_e4m3((w >> (sh + 8)) & 0xFF);
    return r;
#endif
}

// ---- OCP e4m3 encode (one-time kernel; manual RNE, matches HW decode) ----
__device__ unsigned enc_e4m3(float x) {
    float a = fabsf(x);
    unsigned s = (__builtin_bit_cast(unsigned, x) >> 31) << 7;
    if (a >= 448.0f) return s | 0x7E;          // clamp to max finite
    if (a < 0.015625f) {                        // subnormal quantum 2^-9
        int m = (int)rintf(a * 512.0f);
        return s | (unsigned)(m > 7 ? 8 : m);
    }
    int e; float fr = frexpf(a, &e);            // a = fr*2^e, fr in [0.5,1)
    int q = (int)rintf(fr * 16.0f);             // 1.mmm * 8, RNE
    if (q == 16) { q = 8; e++; }
    int e8 = e - 1 + 7;
    if (e8 > 15 || (e8 == 15 && (q - 8) > 6)) return s | 0x7E;
    return s | (unsigned)(e8 << 3) | (unsigned)(q - 8);
}

// ---------------- f32 -> fp8(e4m3, x256) conversion for W_hh ----------------
__global__ void convert_f32_fp8(const float* __restrict__ in,
                                unsigned* __restrict__ out, int n4) {
    int i = blockIdx.x * blockDim.x + threadIdx.x;
    int stride = gridDim.x * blockDim.x;
    for (; i < n4; i += stride) {
        f32x4 v = *(const f32x4*)(in + (size_t)i * 4);
        unsigned b0 = enc_e4m3(v[0] * W_SCALE);
        unsigned b1 = enc_e4m3(v[1] * W_SCALE);
        unsigned b2 = enc_e4m3(v[2] * W_SCALE);
        unsigned b3 = enc_e4m3(v[3] * W_SCALE);
        out[i] = b0 | (b1 << 8) | (b2 << 16) | (b3 << 24);
    }
}

__global__ void zero_f32(float* __restrict__ p, int n) {
    int i = blockIdx.x * blockDim.x + threadIdx.x;
    int stride = gridDim.x * blockDim.x;
    for (; i < n; i += stride) p[i] = 0.0f;
}

// ---------------- GEMM: G[t][r] = sum_k X[t][k]*W_ih[r][k] + bih[r]+bhh[r] ----------------
__device__ __forceinline__ short8 cvt8(const float* __restrict__ p) {
    f32x4 a = *(const f32x4*)p;
    f32x4 b = *(const f32x4*)(p + 4);
    short8 r;
    r[0] = (short)f2bf(a[0]); r[1] = (short)f2bf(a[1]);
    r[2] = (short)f2bf(a[2]); r[3] = (short)f2bf(a[3]);
    r[4] = (short)f2bf(b[0]); r[5] = (short)f2bf(b[1]);
    r[6] = (short)f2bf(b[2]); r[7] = (short)f2bf(b[3]);
    return r;
}

__global__ __launch_bounds__(256) void gemm_bt(const float* __restrict__ A,
                                               const float* __restrict__ B,
                                               const float* __restrict__ bih,
                                               const float* __restrict__ bhh,
                                               _Float16* __restrict__ C,
                                               int M, int N, int K) {
    __shared__ unsigned short As[128 * 32];
    __shared__ unsigned short Bs[128 * 32];
    const int bn = blockIdx.x, bm = blockIdx.y;
    const int tid = threadIdx.x;
    const int w = tid >> 6, l = tid & 63;
    const int wm = (w >> 1) * 64, wn = (w & 1) * 64;
    const int lr = l & 15, lk = (l >> 4) * 8;

    f32x4 acc[4][4];
#pragma unroll
    for (int mi = 0; mi < 4; mi++)
#pragma unroll
        for (int ni = 0; ni < 4; ni++) acc[mi][ni] = (f32x4)0.0f;

    const float* Ablk = A + (size_t)bm * 128 * K;
    const float* Bblk = B + (size_t)bn * 128 * K;

    for (int k0 = 0; k0 < K; k0 += 32) {
#pragma unroll
        for (int s = 0; s < 2; ++s) {
            int ch = tid + s * 256;
            int r = ch >> 2, kc = (ch & 3) * 8;
            ((short8*)As)[ch] = cvt8(Ablk + (size_t)r * K + k0 + kc);
            ((short8*)Bs)[ch] = cvt8(Bblk + (size_t)r * K + k0 + kc);
        }
        __syncthreads();
        short8 af[4], bfr[4];
#pragma unroll
        for (int mi = 0; mi < 4; mi++)
            af[mi] = *(const short8*)&As[(wm + mi * 16 + lr) * 32 + lk];
#pragma unroll
        for (int ni = 0; ni < 4; ni++)
            bfr[ni] = *(const short8*)&Bs[(wn + ni * 16 + lr) * 32 + lk];
#pragma unroll
        for (int mi = 0; mi < 4; mi++)
#pragma unroll
            for (int ni = 0; ni < 4; ni++)
                acc[mi][ni] = __builtin_amdgcn_mfma_f32_16x16x32_bf16(
                    af[mi], bfr[ni], acc[mi][ni], 0, 0, 0);
        __syncthreads();
    }

    const int cr = (l >> 4) * 4, cc = l & 15;
#pragma unroll
    for (int mi = 0; mi < 4; mi++) {
#pragma unroll
        for (int ni = 0; ni < 4; ni++) {
            int col = bn * 128 + wn + ni * 16 + cc;
            float bias = bih[col] + bhh[col];
#pragma unroll
            for (int r = 0; r < 4; r++) {
                int row = bm * 128 + wm + mi * 16 + cr + r;
                C[(size_t)row * N + col] = (_Float16)(acc[mi][ni][r] + bias);
            }
        }
    }
}

// ---------------- Persistent recurrent kernel (fp8 weights on-chip) ----------------
// 256 WGs x 512 threads, 1 WG/CU. WG b owns 64 W_hh rows {g*4096+16b+u}, fp8 x256.
// Cols 0..2047: 64 parked dwords/thread (opaque asm loads; pressure ~110 -> RA keeps).
// Cols 2048..4095: LDS 128 KiB. Decode per use via v_cvt_pk_f32_fp8, f32 fma accum.
// r4-r6 lesson: 192 parked dwords always got spilled -> 96 MB/step L3 stream at
// ~11 TB/s == the entire 8.5us step. 64 dwords is inside the RA's comfort zone.
__global__ __launch_bounds__(512, 2) void lstm_seq(
        const unsigned char* __restrict__ W8,  // fp8 [16384][4096], value*256
        const _Float16* __restrict__ G,        // f16 [2048][16384]
        const float* __restrict__ Wlin,        // [4096]
        _Float16* __restrict__ hbuf,           // f16 [2][4096]
        unsigned* __restrict__ flags,          // [256*FLAG_STRIDE]
        float* __restrict__ praw_part) {       // [256][2048]
    extern __shared__ char smem[];
    unsigned char* wl8 = (unsigned char*)smem;        // [64][2048] fp8 = 128 KiB
    _Float16* hl  = (_Float16*)(smem + 131072);       // [4096] f16  = 8 KiB
    float*    part = (float*)(smem + 131072 + 8192);  // [64][65]    = 16.25 KiB
    unsigned* hl32 = (unsigned*)hl;

    const int tid = threadIdx.x;
    const int w = tid >> 6, l = tid & 63;
    const int bid = blockIdx.x;
    const int base = bid * 16;

    // ---- one-time: park cols 0..2047 (fp8) in 64 VGPRs via opaque loads ----
    u32x2 wq[8][4];
#pragma unroll
    for (int rr = 0; rr < 8; ++rr) {
        const int rl = w * 8 + rr;
        const size_t grow = (size_t)((rl >> 4) * H_DIM + base + (rl & 15));
        const unsigned char* wp = W8 + grow * 4096 + l * 8;
#pragma unroll
        for (int c = 0; c < 4; ++c) {
            u32x2 tmp;
            asm volatile("global_load_dwordx2 %0, %1, off"
                         : "=v"(tmp) : "v"(wp + c * 512));
            wq[rr][c] = tmp;
        }
    }
    asm volatile("s_waitcnt vmcnt(0)" ::: "memory");
    __builtin_amdgcn_sched_barrier(0);

    // ---- LDS stage cols 2048..4095 (fp8): 32768 dwords ----
    for (int i = tid; i < 32768; i += 512) {
        int r = i >> 9, cd = i & 511;
        size_t grow = (size_t)((r >> 4) * H_DIM + base + (r & 15));
        ((unsigned*)wl8)[r * 512 + cd] =
            *(const unsigned*)(W8 + grow * 4096 + 2048 + cd * 4);
    }

    // loop-invariant hoists
    const float wlin = (tid < 16) ? Wlin[base + tid] : 0.0f;
    const int grow_g = (tid >> 4) * H_DIM + base + (tid & 15);  // valid for tid<64
    const unsigned char* wlbase = wl8 + (size_t)(w * 8) * 2048 + l * 8;
    const _Float16* hlbase = hl + l * 8;
    unsigned short* hb16 = (unsigned short*)hbuf;

    float creg = 0.0f;

#pragma unroll 1
    for (int t = 0; t < T_STEPS; ++t) {
        float gval = 0.0f;
        if (tid < 64) gval = (float)G[(size_t)t * G_DIM + grow_g];

        // ---- h readback: agent-scope coalesced u32 loads -> LDS ----
        const unsigned* hsrc = (const unsigned*)hbuf + ((t & 1) << 11); // 2048 u32
#pragma unroll
        for (int k = 0; k < 4; ++k)
            hl32[k * 512 + tid] = __hip_atomic_load(hsrc + k * 512 + tid,
                                                    __ATOMIC_RELAXED,
                                                    __HIP_MEMORY_SCOPE_AGENT);
        __syncthreads();

        float acc[8];
#pragma unroll
        for (int rr = 0; rr < 8; ++rr) acc[rr] = 0.0f;

        // ---- register chunks: cols c*512 + l*8, c = 0..3 ----
#pragma unroll
        for (int c = 0; c < 4; ++c) {
            half8_t hv = *(const half8_t*)(hlbase + c * 512);
            float h0 = (float)hv[0], h1 = (float)hv[1], h2 = (float)hv[2], h3 = (float)hv[3];
            float h4 = (float)hv[4], h5 = (float)hv[5], h6 = (float)hv[6], h7 = (float)hv[7];
#pragma unroll
            for (int rr = 0; rr < 8; ++rr) {
                f32x2 w01 = fp8pair_f32<false>(wq[rr][c][0]);
                f32x2 w23 = fp8pair_f32<true >(wq[rr][c][0]);
                f32x2 w45 = fp8pair_f32<false>(wq[rr][c][1]);
                f32x2 w67 = fp8pair_f32<true >(wq[rr][c][1]);
                acc[rr] = fmaf(w01[0], h0, acc[rr]);
                acc[rr] = fmaf(w01[1], h1, acc[rr]);
                acc[rr] = fmaf(w23[0], h2, acc[rr]);
                acc[rr] = fmaf(w23[1], h3, acc[rr]);
                acc[rr] = fmaf(w45[0], h4, acc[rr]);
                acc[rr] = fmaf(w45[1], h5, acc[rr]);
                acc[rr] = fmaf(w67[0], h6, acc[rr]);
                acc[rr] = fmaf(w67[1], h7, acc[rr]);
            }
        }
        // ---- LDS chunks: cols 2048 + c*512 + l*8, c = 0..3 ----
#pragma unroll
        for (int c = 0; c < 4; ++c) {
            half8_t hv = *(const half8_t*)(hlbase + (4 + c) * 512);
            float h0 = (float)hv[0], h1 = (float)hv[1], h2 = (float)hv[2], h3 = (float)hv[3];
            float h4 = (float)hv[4], h5 = (float)hv[5], h6 = (float)hv[6], h7 = (float)hv[7];
#pragma unroll
            for (int rr = 0; rr < 8; ++rr) {
                u32x2 wv = *(const u32x2*)(wlbase + rr * 2048 + c * 512);
                f32x2 w01 = fp8pair_f32<false>(wv[0]);
                f32x2 w23 = fp8pair_f32<true >(wv[0]);
                f32x2 w45 = fp8pair_f32<false>(wv[1]);
                f32x2 w67 = fp8pair_f32<true >(wv[1]);
                acc[rr] = fmaf(w01[0], h0, acc[rr]);
                acc[rr] = fmaf(w01[1], h1, acc[rr]);
                acc[rr] = fmaf(w23[0], h2, acc[rr]);
                acc[rr] = fmaf(w23[1], h3, acc[rr]);
                acc[rr] = fmaf(w45[0], h4, acc[rr]);
                acc[rr] = fmaf(w45[1], h5, acc[rr]);
                acc[rr] = fmaf(w67[0], h6, acc[rr]);
                acc[rr] = fmaf(w67[1], h7, acc[rr]);
            }
        }
#pragma unroll
        for (int rr = 0; rr < 8; ++rr)
            part[(w * 8 + rr) * 65 + l] = acc[rr];
        __syncthreads();

        if (tid < 64) {
            const float* pr = part + tid * 65;
            float s0 = 0.f, s1 = 0.f, s2 = 0.f, s3 = 0.f;
#pragma unroll
            for (int j = 0; j < 16; ++j) {
                s0 += pr[4 * j + 0]; s1 += pr[4 * j + 1];
                s2 += pr[4 * j + 2]; s3 += pr[4 * j + 3];
            }
            float s = ((s0 + s1) + (s2 + s3)) * W_INV_SCALE + gval;
            float fv = __shfl(s, (tid & 15) + 16);
            float gv = __shfl(s, (tid & 15) + 32);
            float ov = __shfl(s, (tid & 15) + 48);
            if (tid < 16) {
                float c = sigmoidf_(fv) * creg + sigmoidf_(s) * tanhf(gv);
                creg = c;
                float hv = sigmoidf_(ov) * tanhf(c);
                unsigned short hb = __builtin_bit_cast(unsigned short, (_Float16)hv);
                __hip_atomic_store(hb16 + (((t + 1) & 1) << 12) + base + tid, hb,
                                   __ATOMIC_RELAXED, __HIP_MEMORY_SCOPE_AGENT);
                float pp = hv * wlin;
                pp += __shfl_xor(pp, 8, 16);
                pp += __shfl_xor(pp, 4, 16);
                pp += __shfl_xor(pp, 2, 16);
                pp += __shfl_xor(pp, 1, 16);
                if (tid == 0) praw_part[(size_t)bid * T_STEPS + t] = pp;
            }
        }

        // ---- fence-free device barrier (wave 0 spins, others park) ----
        if (w == 0) {
            asm volatile("s_waitcnt vmcnt(0)" ::: "memory");
            if (tid == 0)
                __hip_atomic_store(flags + (size_t)bid * FLAG_STRIDE, (unsigned)(t + 1),
                                   __ATOMIC_RELAXED, __HIP_MEMORY_SCOPE_AGENT);
            const unsigned tgt = (unsigned)(t + 1);
            for (;;) {
                unsigned f0 = __hip_atomic_load(flags + (size_t)l * FLAG_STRIDE,         __ATOMIC_RELAXED, __HIP_MEMORY_SCOPE_AGENT);
                unsigned f1 = __hip_atomic_load(flags + (size_t)(l + 64) * FLAG_STRIDE,  __ATOMIC_RELAXED, __HIP_MEMORY_SCOPE_AGENT);
                unsigned f2 = __hip_atomic_load(flags + (size_t)(l + 128) * FLAG_STRIDE, __ATOMIC_RELAXED, __HIP_MEMORY_SCOPE_AGENT);
                unsigned f3 = __hip_atomic_load(flags + (size_t)(l + 192) * FLAG_STRIDE, __ATOMIC_RELAXED, __HIP_MEMORY_SCOPE_AGENT);
                bool ok = (f0 >= tgt) & (f1 >= tgt) & (f2 >= tgt) & (f3 >= tgt);
                if (__all(ok)) break;
                __builtin_amdgcn_s_sleep(1);
            }
        }
        __syncthreads();
    }
}

__global__ void finalize_out(const float* __restrict__ praw_part,
                             const float* __restrict__ blin,
                             float* __restrict__ out, int n) {
    int i = blockIdx.x * blockDim.x + threadIdx.x;
    if (i < n) {
        float s = blin[0];
        for (int wg = 0; wg < 256; ++wg)
            s += praw_part[(size_t)wg * T_STEPS + i];
        out[i] = 1.0f / (1.0f + __expf(-s));
    }
}

// ---------------- launch ----------------
extern "C" void kernel_launch(void* const* d_in, const int* in_sizes, int n_in,
                              void* d_out, int out_size, void* d_ws, size_t ws_size,
                              hipStream_t stream) {
    const float* X    = (const float*)d_in[0];   // [2048][2048]
    const float* Wih  = (const float*)d_in[1];   // [16384][2048]
    const float* Whh  = (const float*)d_in[2];   // [16384][4096]
    const float* bih  = (const float*)d_in[3];   // [16384]
    const float* bhh  = (const float*)d_in[4];   // [16384]
    const float* Wlin = (const float*)d_in[5];   // [4096]
    const float* blin = (const float*)d_in[6];   // [1]
    float* out = (float*)d_out;                  // [2048]

    char* ws = (char*)d_ws;
    // layout (bytes):
    //   W8  (fp8) : 0         .. 67108864   (16384*4096)
    //   G   (f16) : 67108864  .. 134217728  (2048*16384*2)
    //   flags     : 134217728 .. +32768     (256*32 u32, 128B-padded)
    //   hbuf (f16): 134250496 .. +16384     (2*4096*2)
    //   praw_part : 134266880 .. +2097152   (256*2048*4)
    unsigned char* W8 = (unsigned char*)(ws);
    _Float16* G     = (_Float16*)(ws + 67108864);
    unsigned* flags = (unsigned*)(ws + 134217728);
    _Float16* hbuf  = (_Float16*)(ws + 134250496);
    float* praw_part = (float*)(ws + 134266880);

    convert_f32_fp8<<<dim3(2048), dim3(256), 0, stream>>>(Whh, (unsigned*)W8,
                                                          (16384 * 4096) / 4);
    // zero flags (32 KiB) + both h parity buffers (16 KiB) = 12288 floats
    zero_f32<<<dim3(48), dim3(256), 0, stream>>>((float*)flags, 12288);
    gemm_bt<<<dim3(128, 16), dim3(256), 0, stream>>>(X, Wih, bih, bhh, G,
                                                     2048, 16384, 2048);

    hipFuncSetAttribute((const void*)lstm_seq,
                        hipFuncAttributeMaxDynamicSharedMemorySize, 160 * 1024);

    void* args[] = { (void*)&W8, (void*)&G, (void*)&Wlin,
                     (void*)&hbuf, (void*)&flags, (void*)&praw_part };
    hipLaunchCooperativeKernel((void*)lstm_seq, dim3(256), dim3(512),
                               args, 155904, stream);

    finalize_out<<<dim3(8), dim3(256), 0, stream>>>(praw_part, blin, out, 2048);
}

// Round 9
// 23223.683 us; speedup vs baseline: 1.2869x; 1.2869x over previous
//
#include <hip/hip_runtime.h>

typedef short  short8 __attribute__((ext_vector_type(8)));
typedef float  f32x4  __attribute__((ext_vector_type(4)));
typedef float  f32x2  __attribute__((ext_vector_type(2)));
typedef _Float16 half8_t __attribute__((ext_vector_type(8)));
typedef unsigned int u32x4 __attribute__((ext_vector_type(4)));

#define T_STEPS 2048
#define I_DIM   2048
#define H_DIM   4096
#define G_DIM   16384   // 4*H
#define W_SCALE     256.0f
#define W_INV_SCALE (1.0f / 256.0f)

__device__ __forceinline__ unsigned short f2bf(float x) {
    union { float f; unsigned int u; } v; v.f = x;
    unsigned int u = v.u;
    return (unsigned short)((u + 0x7FFFu + ((u >> 16) & 1u)) >> 16);
}
__device__ __forceinline__ float sigmoidf_(float x) {
    return 1.0f / (1.0f + __expf(-x));
}

// ---- OCP e4m3 decode (HW cvt; word-select is a template literal) ----
__device__ __forceinline__ float dec1_e4m3(unsigned b) {
    int e = (b >> 3) & 15, m = b & 7;
    float v = (e == 0) ? ldexpf((float)m, -9) : ldexpf((float)(8 + m), e - 10);
    return (b & 0x80) ? -v : v;
}
template <bool HI>
__device__ __forceinline__ f32x2 fp8pair_f32(unsigned w) {
#if __has_builtin(__builtin_amdgcn_cvt_pk_f32_fp8)
    return __builtin_amdgcn_cvt_pk_f32_fp8((int)w, HI);
#else
    unsigned sh = HI ? 16u : 0u;
    f32x2 r;
    r[0] = dec1_e4m3((w >> sh) & 0xFF);
    r[1] = dec1_e4m3((w >> (sh + 8)) & 0xFF);
    return r;
#endif
}

// ---- OCP e4m3 encode (one-time kernel; manual RNE, matches HW decode) ----
__device__ unsigned enc_e4m3(float x) {
    float a = fabsf(x);
    unsigned s = (__builtin_bit_cast(unsigned, x) >> 31) << 7;
    if (a >= 448.0f) return s | 0x7E;
    if (a < 0.015625f) {
        int m = (int)rintf(a * 512.0f);
        return s | (unsigned)(m > 7 ? 8 : m);
    }
    int e; float fr = frexpf(a, &e);
    int q = (int)rintf(fr * 16.0f);
    if (q == 16) { q = 8; e++; }
    int e8 = e - 1 + 7;
    if (e8 > 15 || (e8 == 15 && (q - 8) > 6)) return s | 0x7E;
    return s | (unsigned)(e8 << 3) | (unsigned)(q - 8);
}

__global__ void convert_f32_fp8(const float* __restrict__ in,
                                unsigned* __restrict__ out, int n4) {
    int i = blockIdx.x * blockDim.x + threadIdx.x;
    int stride = gridDim.x * blockDim.x;
    for (; i < n4; i += stride) {
        f32x4 v = *(const f32x4*)(in + (size_t)i * 4);
        unsigned b0 = enc_e4m3(v[0] * W_SCALE);
        unsigned b1 = enc_e4m3(v[1] * W_SCALE);
        unsigned b2 = enc_e4m3(v[2] * W_SCALE);
        unsigned b3 = enc_e4m3(v[3] * W_SCALE);
        out[i] = b0 | (b1 << 8) | (b2 << 16) | (b3 << 24);
    }
}

__global__ void zero_f32(float* __restrict__ p, int n) {
    int i = blockIdx.x * blockDim.x + threadIdx.x;
    int stride = gridDim.x * blockDim.x;
    for (; i < n; i += stride) p[i] = 0.0f;
}

// ---------------- GEMM: G[t][r] = sum_k X[t][k]*W_ih[r][k] + bih[r]+bhh[r] ----------------
__device__ __forceinline__ short8 cvt8(const float* __restrict__ p) {
    f32x4 a = *(const f32x4*)p;
    f32x4 b = *(const f32x4*)(p + 4);
    short8 r;
    r[0] = (short)f2bf(a[0]); r[1] = (short)f2bf(a[1]);
    r[2] = (short)f2bf(a[2]); r[3] = (short)f2bf(a[3]);
    r[4] = (short)f2bf(b[0]); r[5] = (short)f2bf(b[1]);
    r[6] = (short)f2bf(b[2]); r[7] = (short)f2bf(b[3]);
    return r;
}

__global__ __launch_bounds__(256) void gemm_bt(const float* __restrict__ A,
                                               const float* __restrict__ B,
                                               const float* __restrict__ bih,
                                               const float* __restrict__ bhh,
                                               _Float16* __restrict__ C,
                                               int M, int N, int K) {
    __shared__ unsigned short As[128 * 32];
    __shared__ unsigned short Bs[128 * 32];
    const int bn = blockIdx.x, bm = blockIdx.y;
    const int tid = threadIdx.x;
    const int w = tid >> 6, l = tid & 63;
    const int wm = (w >> 1) * 64, wn = (w & 1) * 64;
    const int lr = l & 15, lk = (l >> 4) * 8;

    f32x4 acc[4][4];
#pragma unroll
    for (int mi = 0; mi < 4; mi++)
#pragma unroll
        for (int ni = 0; ni < 4; ni++) acc[mi][ni] = (f32x4)0.0f;

    const float* Ablk = A + (size_t)bm * 128 * K;
    const float* Bblk = B + (size_t)bn * 128 * K;

    for (int k0 = 0; k0 < K; k0 += 32) {
#pragma unroll
        for (int s = 0; s < 2; ++s) {
            int ch = tid + s * 256;
            int r = ch >> 2, kc = (ch & 3) * 8;
            ((short8*)As)[ch] = cvt8(Ablk + (size_t)r * K + k0 + kc);
            ((short8*)Bs)[ch] = cvt8(Bblk + (size_t)r * K + k0 + kc);
        }
        __syncthreads();
        short8 af[4], bfr[4];
#pragma unroll
        for (int mi = 0; mi < 4; mi++)
            af[mi] = *(const short8*)&As[(wm + mi * 16 + lr) * 32 + lk];
#pragma unroll
        for (int ni = 0; ni < 4; ni++)
            bfr[ni] = *(const short8*)&Bs[(wn + ni * 16 + lr) * 32 + lk];
#pragma unroll
        for (int mi = 0; mi < 4; mi++)
#pragma unroll
            for (int ni = 0; ni < 4; ni++)
                acc[mi][ni] = __builtin_amdgcn_mfma_f32_16x16x32_bf16(
                    af[mi], bfr[ni], acc[mi][ni], 0, 0, 0);
        __syncthreads();
    }

    const int cr = (l >> 4) * 4, cc = l & 15;
#pragma unroll
    for (int mi = 0; mi < 4; mi++) {
#pragma unroll
        for (int ni = 0; ni < 4; ni++) {
            int col = bn * 128 + wn + ni * 16 + cc;
            float bias = bih[col] + bhh[col];
#pragma unroll
            for (int r = 0; r < 4; r++) {
                int row = bm * 128 + wm + mi * 16 + cr + r;
                C[(size_t)row * N + col] = (_Float16)(acc[mi][ni][r] + bias);
            }
        }
    }
}

// ---------------- Persistent recurrent kernel (no parked registers) ----------------
// 256 WGs x 512 threads, 1 WG/CU. WG b owns 64 W_hh rows {g*4096+16b+u}, fp8 x256.
// Cols 0..2047 in LDS (128 KiB, staged once). Cols 2048..4095 re-streamed EVERY
// step via in-loop volatile global_load_dwordx4 (short live ranges; per-XCD
// footprint 4 MB ~ L2 -> L2-hot). r2-r8 lesson: any long-lived register state
// gets spilled by the RA (r8: scratch reloads went to HBM at 300 GB/s = the
// whole step). Row sums via full-wave shfl_xor butterfly (no LDS transpose).
__global__ __launch_bounds__(512, 2) void lstm_seq(
        const unsigned char* __restrict__ W8,  // fp8 [16384][4096], value*256
        const _Float16* __restrict__ G,        // f16 [2048][16384]
        const float* __restrict__ Wlin,        // [4096]
        _Float16* __restrict__ hbuf,           // f16 [2][4096]
        unsigned* __restrict__ flags,          // [256]
        float* __restrict__ praw_part) {       // [256][2048]
    extern __shared__ char smem[];
    unsigned char* wl8 = (unsigned char*)smem;        // [64][2048] fp8 = 128 KiB
    _Float16* hl = (_Float16*)(smem + 131072);        // [4096] f16 = 8 KiB
    float* gsum = (float*)(smem + 131072 + 8192);     // [64] f32
    unsigned* hl32 = (unsigned*)hl;

    const int tid = threadIdx.x;
    const int w = tid >> 6, l = tid & 63;
    const int bid = blockIdx.x;
    const int base = bid * 16;

    // ---- one-time LDS stage: cols 0..2047 of the WG's 64 rows ----
    for (int i = tid; i < 8192; i += 512) {   // 16B units: 64 rows x 128
        int rl = i >> 7, k = i & 127;
        size_t grow = (size_t)((rl >> 4) * H_DIM + base + (rl & 15));
        *(u32x4*)(wl8 + rl * 2048 + k * 16) =
            *(const u32x4*)(W8 + grow * 4096 + k * 16);
    }

    // per-row streamed base pointers (cols 2048+, this lane's 16B slice)
    const unsigned char* wrow[8];
#pragma unroll
    for (int rr = 0; rr < 8; ++rr) {
        int rl = w * 8 + rr;
        size_t grow = (size_t)((rl >> 4) * H_DIM + base + (rl & 15));
        wrow[rr] = W8 + grow * 4096 + 2048 + l * 16;
    }

    const float wlin = (tid < 16) ? Wlin[base + tid] : 0.0f;
    const int grow_g = (tid >> 4) * H_DIM + base + (tid & 15);  // valid tid<64
    unsigned short* hb16 = (unsigned short*)hbuf;

    float creg = 0.0f;

// decode 16 fp8 weights (u32x4) against h slice hf[16], accumulate into a
#define DOT16(a, wv, hf)                                              \
    {                                                                 \
        _Pragma("unroll")                                             \
        for (int d = 0; d < 4; ++d) {                                 \
            f32x2 lo_ = fp8pair_f32<false>((wv)[d]);                  \
            f32x2 hi_ = fp8pair_f32<true >((wv)[d]);                  \
            (a) = fmaf(lo_[0], (hf)[d * 4 + 0], (a));                 \
            (a) = fmaf(lo_[1], (hf)[d * 4 + 1], (a));                 \
            (a) = fmaf(hi_[0], (hf)[d * 4 + 2], (a));                 \
            (a) = fmaf(hi_[1], (hf)[d * 4 + 3], (a));                 \
        }                                                             \
    }

#define LOAD_HF(p, hf)                                                \
    {                                                                 \
        const _Float16* hp_ = hl + (p) * 1024 + l * 16;               \
        half8_t ha_ = *(const half8_t*)hp_;                           \
        half8_t hb_ = *(const half8_t*)(hp_ + 8);                     \
        _Pragma("unroll")                                             \
        for (int j = 0; j < 8; ++j) {                                 \
            (hf)[j] = (float)ha_[j];                                  \
            (hf)[8 + j] = (float)hb_[j];                              \
        }                                                             \
    }

#pragma unroll 1
    for (int t = 0; t < T_STEPS; ++t) {
        // prefetch input-projection values (wave 0 only)
        float gval = 0.0f;
        if (tid < 64) gval = (float)G[(size_t)t * G_DIM + grow_g];

        // ---- h readback: agent-scope coalesced u32 loads -> LDS ----
        const unsigned* hsrc = (const unsigned*)hbuf + ((t & 1) << 11);
#pragma unroll
        for (int k = 0; k < 4; ++k)
            hl32[k * 512 + tid] = __hip_atomic_load(hsrc + k * 512 + tid,
                                                    __ATOMIC_RELAXED,
                                                    __HIP_MEMORY_SCOPE_AGENT);
        __syncthreads();

        float acc[8];
#pragma unroll
        for (int rr = 0; rr < 8; ++rr) acc[rr] = 0.0f;

        u32x4 wg[8];
        // issue streamed loads for position 2 (cols 2048..3071)
#pragma unroll
        for (int rr = 0; rr < 8; ++rr)
            asm volatile("global_load_dwordx4 %0, %1, off"
                         : "=v"(wg[rr]) : "v"(wrow[rr]));

        {   // LDS position 0 (cols 0..1023)
            float hf[16];
            LOAD_HF(0, hf);
#pragma unroll
            for (int rr = 0; rr < 8; ++rr) {
                u32x4 wv = *(const u32x4*)(wl8 + (w * 8 + rr) * 2048 + l * 16);
                DOT16(acc[rr], wv, hf);
            }
        }
        asm volatile("s_waitcnt vmcnt(0)" ::: "memory");
        __builtin_amdgcn_sched_barrier(0);
        {   // streamed position 2
            float hf[16];
            LOAD_HF(2, hf);
#pragma unroll
            for (int rr = 0; rr < 8; ++rr) DOT16(acc[rr], wg[rr], hf);
        }
        // issue streamed loads for position 3 (cols 3072..4095)
#pragma unroll
        for (int rr = 0; rr < 8; ++rr)
            asm volatile("global_load_dwordx4 %0, %1, off"
                         : "=v"(wg[rr]) : "v"(wrow[rr] + 1024));
        {   // LDS position 1 (cols 1024..2047)
            float hf[16];
            LOAD_HF(1, hf);
#pragma unroll
            for (int rr = 0; rr < 8; ++rr) {
                u32x4 wv = *(const u32x4*)(wl8 + (w * 8 + rr) * 2048 + 1024 + l * 16);
                DOT16(acc[rr], wv, hf);
            }
        }
        asm volatile("s_waitcnt vmcnt(0)" ::: "memory");
        __builtin_amdgcn_sched_barrier(0);
        {   // streamed position 3
            float hf[16];
            LOAD_HF(3, hf);
#pragma unroll
            for (int rr = 0; rr < 8; ++rr) DOT16(acc[rr], wg[rr], hf);
        }

        // ---- full-wave butterfly reduce; lane rr stores row w*8+rr ----
#pragma unroll
        for (int rr = 0; rr < 8; ++rr) {
            float v = acc[rr];
            v += __shfl_xor(v, 1);
            v += __shfl_xor(v, 2);
            v += __shfl_xor(v, 4);
            v += __shfl_xor(v, 8);
            v += __shfl_xor(v, 16);
            v += __shfl_xor(v, 32);
            if (l == rr) gsum[w * 8 + rr] = v;
        }
        __syncthreads();

        if (tid < 64) {
            float s = gsum[tid] * W_INV_SCALE + gval;
            float fv = __shfl(s, (tid & 15) + 16);
            float gv = __shfl(s, (tid & 15) + 32);
            float ov = __shfl(s, (tid & 15) + 48);
            if (tid < 16) {
                float c = sigmoidf_(fv) * creg + sigmoidf_(s) * tanhf(gv);
                creg = c;
                float hv = sigmoidf_(ov) * tanhf(c);
                unsigned short hb = __builtin_bit_cast(unsigned short, (_Float16)hv);
                __hip_atomic_store(hb16 + (((t + 1) & 1) << 12) + base + tid, hb,
                                   __ATOMIC_RELAXED, __HIP_MEMORY_SCOPE_AGENT);
                float pp = hv * wlin;
                pp += __shfl_xor(pp, 8, 16);
                pp += __shfl_xor(pp, 4, 16);
                pp += __shfl_xor(pp, 2, 16);
                pp += __shfl_xor(pp, 1, 16);
                if (tid == 0) praw_part[(size_t)bid * T_STEPS + t] = pp;
            }
        }

        // ---- fence-free device barrier (wave 0 spins, others park) ----
        if (w == 0) {
            asm volatile("s_waitcnt vmcnt(0)" ::: "memory");
            if (tid == 0)
                __hip_atomic_store(flags + bid, (unsigned)(t + 1),
                                   __ATOMIC_RELAXED, __HIP_MEMORY_SCOPE_AGENT);
            const unsigned tgt = (unsigned)(t + 1);
            for (;;) {
                unsigned f0 = __hip_atomic_load(flags + l,       __ATOMIC_RELAXED, __HIP_MEMORY_SCOPE_AGENT);
                unsigned f1 = __hip_atomic_load(flags + l + 64,  __ATOMIC_RELAXED, __HIP_MEMORY_SCOPE_AGENT);
                unsigned f2 = __hip_atomic_load(flags + l + 128, __ATOMIC_RELAXED, __HIP_MEMORY_SCOPE_AGENT);
                unsigned f3 = __hip_atomic_load(flags + l + 192, __ATOMIC_RELAXED, __HIP_MEMORY_SCOPE_AGENT);
                bool ok = (f0 >= tgt) & (f1 >= tgt) & (f2 >= tgt) & (f3 >= tgt);
                if (__all(ok)) break;
                __builtin_amdgcn_s_sleep(1);
            }
        }
        __syncthreads();
    }
#undef DOT16
#undef LOAD_HF
}

__global__ void finalize_out(const float* __restrict__ praw_part,
                             const float* __restrict__ blin,
                             float* __restrict__ out, int n) {
    int i = blockIdx.x * blockDim.x + threadIdx.x;
    if (i < n) {
        float s = blin[0];
        for (int wg = 0; wg < 256; ++wg)
            s += praw_part[(size_t)wg * T_STEPS + i];
        out[i] = 1.0f / (1.0f + __expf(-s));
    }
}

// ---------------- launch ----------------
extern "C" void kernel_launch(void* const* d_in, const int* in_sizes, int n_in,
                              void* d_out, int out_size, void* d_ws, size_t ws_size,
                              hipStream_t stream) {
    const float* X    = (const float*)d_in[0];   // [2048][2048]
    const float* Wih  = (const float*)d_in[1];   // [16384][2048]
    const float* Whh  = (const float*)d_in[2];   // [16384][4096]
    const float* bih  = (const float*)d_in[3];   // [16384]
    const float* bhh  = (const float*)d_in[4];   // [16384]
    const float* Wlin = (const float*)d_in[5];   // [4096]
    const float* blin = (const float*)d_in[6];   // [1]
    float* out = (float*)d_out;                  // [2048]

    char* ws = (char*)d_ws;
    // layout (bytes):
    //   W8  (fp8) : 0         .. 67108864   (16384*4096)
    //   G   (f16) : 67108864  .. 134217728  (2048*16384*2)
    //   flags     : 134217728 .. +1024      (256 u32)
    //   hbuf (f16): 134218752 .. +16384     (2*4096*2)
    //   praw_part : 134235136 .. +2097152   (256*2048*4)
    unsigned char* W8 = (unsigned char*)(ws);
    _Float16* G     = (_Float16*)(ws + 67108864);
    unsigned* flags = (unsigned*)(ws + 134217728);
    _Float16* hbuf  = (_Float16*)(ws + 134218752);
    float* praw_part = (float*)(ws + 134235136);

    convert_f32_fp8<<<dim3(2048), dim3(256), 0, stream>>>(Whh, (unsigned*)W8,
                                                          (16384 * 4096) / 4);
    // zero flags (1 KiB) + both h parity buffers (16 KiB) = 4352 floats
    zero_f32<<<dim3(17), dim3(256), 0, stream>>>((float*)flags, 4352);
    gemm_bt<<<dim3(128, 16), dim3(256), 0, stream>>>(X, Wih, bih, bhh, G,
                                                     2048, 16384, 2048);

    hipFuncSetAttribute((const void*)lstm_seq,
                        hipFuncAttributeMaxDynamicSharedMemorySize, 160 * 1024);

    void* args[] = { (void*)&W8, (void*)&G, (void*)&Wlin,
                     (void*)&hbuf, (void*)&flags, (void*)&praw_part };
    hipLaunchCooperativeKernel((void*)lstm_seq, dim3(256), dim3(512),
                               args, 139520, stream);

    finalize_out<<<dim3(8), dim3(256), 0, stream>>>(praw_part, blin, out, 2048);
}